// Round 8
// baseline (130.398 us; speedup 1.0000x reference)
//
#include <hip/hip_runtime.h>
#include <hip/hip_bf16.h>

// Problem constants (B,H,W,C) = (4,56,56,256), nh=8, K=7, lr=4, hd=32
#define BD 4
#define HD_ 56
#define WD 56
#define CD 256
#define NH 8
#define KW 7
#define LR 4
#define HDIM 32
#define MB (HD_*WD)              // 3136 rows per batch
#define NROWS (BD*MB)            // 12544 total rows
#define QK_PER_B (HD_*WD*32)     // 100352  (q/k per-batch elements)
#define V_PER_B  (HD_*WD*256)    // 802816

typedef short short8 __attribute__((ext_vector_type(8)));   // 8 bf16 (4 VGPRs)
typedef float floatx4 __attribute__((ext_vector_type(4)));  // MFMA C/D

static __device__ inline ushort f2bf(float f) {
    __hip_bfloat16 h = __float2bfloat16(f);
    return *(ushort*)&h;
}
static __device__ inline float bf2f(uint h16) {          // h16 = bf16 in low 16 bits
    union { uint u; float f; } c; c.u = h16 << 16; return c.f;
}
static __device__ inline float bf2f_hi(uint u) {         // bf16 in high 16 bits
    union { uint v; float f; } c; c.v = u & 0xffff0000u; return c.f;
}

// global -> LDS async DMA, 16B per lane. LDS dest is wave-uniform base +
// lane*16 (HW behavior); global src is per-lane.
typedef const __attribute__((address_space(1))) void* gp1_t;
typedef __attribute__((address_space(3))) void* sp3_t;
static __device__ __forceinline__ void glds16(const void* g, void* s) {
    __builtin_amdgcn_global_load_lds((gp1_t)g, (sp3_t)s, 16, 0, 0);
}

// ---------------- prep: x->bf16 + transposed bf16 weights + packed bias -----
__global__ __launch_bounds__(256) void prep_all(
    const float* __restrict__ x,
    const float* __restrict__ Wq, const float* __restrict__ Wk,
    const float* __restrict__ Wv, const float* __restrict__ bq,
    const float* __restrict__ bk, const float* __restrict__ bv,
    const float* __restrict__ Wp,
    ushort* __restrict__ xb, ushort* __restrict__ WpkT,
    ushort* __restrict__ WpT, float* __restrict__ pb)
{
    int idx = blockIdx.x * 256 + threadIdx.x;
    if (idx < 401408) {
        float4 f0 = *(const float4*)&x[idx * 8];
        float4 f1 = *(const float4*)&x[idx * 8 + 4];
        union { ushort h[8]; uint4 u; } p;
        p.h[0] = f2bf(f0.x); p.h[1] = f2bf(f0.y); p.h[2] = f2bf(f0.z); p.h[3] = f2bf(f0.w);
        p.h[4] = f2bf(f1.x); p.h[5] = f2bf(f1.y); p.h[6] = f2bf(f1.z); p.h[7] = f2bf(f1.w);
        *(uint4*)&xb[idx * 8] = p.u;
    } else if (idx < 401408 + 81920) {
        int j = idx - 401408;
        int n = j >> 8, k = j & 255;
        float v;
        if (n < 32)       v = Wq[k * 32 + n];
        else if (n < 64)  v = Wk[k * 32 + (n - 32)];
        else              v = Wv[k * 256 + (n - 64)];
        WpkT[j] = f2bf(v);
    } else if (idx < 401408 + 81920 + 65536) {
        int j = idx - (401408 + 81920);
        int n = j >> 8, k = j & 255;
        WpT[j] = f2bf(Wp[k * 256 + n]);
    } else if (idx < 401408 + 81920 + 65536 + 320) {
        int n = idx - (401408 + 81920 + 65536);
        pb[n] = (n < 32) ? bq[n] : (n < 64) ? bk[n - 32] : bv[n - 64];
    }
}

// ---------------- MFMA GEMM: QKV projection (proven) ------------------------
static __device__ __forceinline__ void gemm_core_128x64(
    const ushort* __restrict__ Ag, const ushort* __restrict__ Bg,
    ushort* As, ushort* Bs, int m0, int n0, int t, floatx4 (&acc)[4][2])
{
    const int lane = t & 63, w = t >> 6;
    const int lx = lane & 7, ly = lane >> 3;
    const int koff = (lx ^ ly) << 3;
    const int col = lane & 15, quad = lane >> 4;
    const int swz = (col & 7) << 4;
    const int wm = w >> 1, wn = w & 1;
    char* Ac = (char*)As;
    char* Bc = (char*)Bs;

    for (int k0 = 0; k0 < 256; k0 += 64) {
        __syncthreads();
#pragma unroll
        for (int l = 0; l < 4; ++l) {
            int c = (w << 2) + l;
            int row = (c << 3) + ly;
            glds16(&Ag[(m0 + row) * 256 + k0 + koff], &As[c << 9]);
        }
#pragma unroll
        for (int l = 0; l < 2; ++l) {
            int c = (w << 1) + l;
            int row = (c << 3) + ly;
            glds16(&Bg[(n0 + row) * 256 + k0 + koff], &Bs[c << 9]);
        }
        __syncthreads();
#pragma unroll
        for (int kk = 0; kk < 2; ++kk) {
            const int kx = ((kk << 6) + (quad << 4)) ^ swz;
            short8 b0 = *(short8*)(Bc + ((wn << 5) + col) * 128 + kx);
            short8 b1 = *(short8*)(Bc + ((wn << 5) + 16 + col) * 128 + kx);
#pragma unroll
            for (int mt = 0; mt < 4; ++mt) {
                short8 a = *(short8*)(Ac + ((wm << 6) + (mt << 4) + col) * 128 + kx);
                acc[mt][0] = __builtin_amdgcn_mfma_f32_16x16x32_bf16(a, b0, acc[mt][0], 0, 0, 0);
                acc[mt][1] = __builtin_amdgcn_mfma_f32_16x16x32_bf16(a, b1, acc[mt][1], 0, 0, 0);
            }
        }
    }
}

__global__ __launch_bounds__(256) void mfma_qkv(
    const ushort* __restrict__ xb, const ushort* __restrict__ Bt,
    const float* __restrict__ pb, ushort* __restrict__ Qb,
    ushort* __restrict__ Kb, ushort* __restrict__ Vb)
{
    __shared__ ushort As[128 * 64];
    __shared__ ushort Bs[64 * 64];
    const int t = threadIdx.x;
    const int m0 = blockIdx.y * 128, n0 = blockIdx.x * 64;

    floatx4 acc[4][2] = {};
    gemm_core_128x64(xb, Bt, As, Bs, m0, n0, t, acc);

    const int lane = t & 63, w = t >> 6;
    const int col = lane & 15, quad = lane >> 4;
    const int wm = w >> 1, wn = w & 1;
#pragma unroll
    for (int mt = 0; mt < 4; ++mt) {
#pragma unroll
        for (int nt = 0; nt < 2; ++nt) {
            int gn = n0 + (wn << 5) + (nt << 4) + col;
            float bias = pb[gn];
#pragma unroll
            for (int rg = 0; rg < 4; ++rg) {
                int m = m0 + (wm << 6) + (mt << 4) + (quad << 2) + rg;
                ushort h = f2bf(acc[mt][nt][rg] + bias);
                if (gn < 32)        Qb[m * 32 + gn] = h;
                else if (gn < 64)   Kb[m * 32 + (gn - 32)] = h;
                else                Vb[m * 256 + (gn - 64)] = h;
            }
        }
    }
}

// ---------------- NATTEN attention v4 — DIAGNOSTIC x3 REPEAT ----------------
// Body identical to round 5/7; executed REP=3 times (idempotent — identical
// values rewritten). Purpose: dispatch dur ~3x27=81us > fills (44us) so the
// top-5 rocprof cut exposes this kernel's counters (Occupancy, VGPR, VALU,
// LDS conflicts, FETCH/WRITE). Load-CSE across reps defeated by asm-opaqued
// zero offset folded into all global base pointers.
__global__ __launch_bounds__(256) void natten_attn4(
    const ushort* __restrict__ Qb, const ushort* __restrict__ Kb,
    const ushort* __restrict__ Vb, const float* __restrict__ rpb,
    ushort* __restrict__ Ab)
{
    __shared__ __align__(16) ushort Pl[32 * 168];   // 10752 B  P[q][key]
    __shared__ __align__(16) ushort Vt[32 * 168];   // 10752 B  V^T[ch][key]
    __shared__ float4 Ksf[140];                     // 2240 B
    __shared__ float  Rs[169];                      // 676 B
    __shared__ float  invS[32];                     // 128 B

    const int tj = blockIdx.x, ti = blockIdx.y;
    const int h = blockIdx.z & 7, b = blockIdx.z >> 3;
    const int t = threadIdx.x;
    const int i0 = ti * 4, j0 = tj * 8;
    const int rs = min(max(i0 - 3, 0), HD_ - 10);
    const int cs = min(max(j0 - 3, 0), WD - 14);

    const ushort* kb0 = Kb + (size_t)b * QK_PER_B + h * (HD_ * WD * LR);
    const ushort* vb0 = Vb + (size_t)b * V_PER_B + h * (HD_ * WD * HDIM);
    const ushort* qb0 = Qb + (size_t)b * QK_PER_B + h * (HD_ * WD * LR);
    const float*  rp0 = rpb + h * 169;

    const int q  = t >> 3, p = t & 7;
    const int qi = q >> 3, qj = q & 7;
    const int i = i0 + qi, j = j0 + qj;
    const int sh = min(max(i - 3, 0), HD_ - KW);
    const int sw = min(max(j - 3, 0), WD - KW);
    const int oh = sh - rs, ow = sw - cs;
    const int rb0 = (sh - i + 6) * 13 + (sw - j + 6);
    const float scale = 0.17677669529663687f;

    const int lane = t & 63, w = t >> 6;
    const int col = lane & 15, quad = lane >> 4;
    const int wm = w & 1, wn = w >> 1;

    size_t off = 0;
#pragma unroll 1
    for (int rep = 0; rep < 3; ++rep) {
        asm volatile("" : "+s"(off));            // opaque 0: defeat load CSE
        const ushort* kb = kb0 + off;
        const ushort* vb = vb0 + off;
        const ushort* qb = qb0 + off;
        const float*  rp = rp0 + off;

        // ---- zero P (window holes + K-pad) and Vt (K-pad)
#pragma unroll
        for (int it = 0; it < 3; ++it) {
            int idx = t + (it << 8);
            if (idx < 672) {
                *(uint4*)&Pl[idx << 3] = make_uint4(0, 0, 0, 0);
                *(uint4*)&Vt[idx << 3] = make_uint4(0, 0, 0, 0);
            }
        }
        __syncthreads();

        // ---- stage K (fp32), rpb, V^T (bf16, oct-major scatter)
        if (t < 140) {
            int r = t / 14, c = t % 14;
            uint2 kr = *(const uint2*)&kb[(rs + r) * (WD * LR) + (cs + c) * LR];
            Ksf[t] = make_float4(bf2f(kr.x & 0xffff), bf2f_hi(kr.x),
                                 bf2f(kr.y & 0xffff), bf2f_hi(kr.y));
        }
        if (t < 169) Rs[t] = rp[t];
#pragma unroll
        for (int it = 0; it < 3; ++it) {
            int idx = t + (it << 8);
            if (idx < 560) {
                int oct = idx / 140, pos = idx % 140;
                int r = pos / 14, c = pos % 14;
                union { uint4 u; ushort hh[8]; } vv;
                vv.u = *(const uint4*)&vb[(rs + r) * (WD * HDIM) + (cs + c) * HDIM + oct * 8];
                ushort* cp = &Vt[(oct * 8) * 168 + pos];
#pragma unroll
                for (int e = 0; e < 8; ++e) cp[e * 168] = vv.hh[e];
            }
        }

        uint2 qr2 = *(const uint2*)&qb[i * (WD * LR) + j * LR];
        __syncthreads();

        // ---- scores: lane p handles kh row p (p==7 idle)
        float qx = bf2f(qr2.x & 0xffff) * scale, qy = bf2f_hi(qr2.x) * scale;
        float qz = bf2f(qr2.y & 0xffff) * scale, qw = bf2f_hi(qr2.y) * scale;

        float sum = 0.f;
        if (p < 7) {
            int kpos  = (oh + p) * 14 + ow;
            int rbase = rb0 + p * 13;
            ushort* prow = &Pl[q * 168 + kpos];
#pragma unroll
            for (int kw = 0; kw < 7; ++kw) {
                float4 kf = Ksf[kpos + kw];
                float d = Rs[rbase + kw];
                d = fmaf(qx, kf.x, d);
                d = fmaf(qy, kf.y, d);
                d = fmaf(qz, kf.z, d);
                d = fmaf(qw, kf.w, d);
                float e = __expf(d);
                sum += e;
                prow[kw] = f2bf(e);
            }
        }
        sum += __shfl_xor(sum, 1);
        sum += __shfl_xor(sum, 2);
        sum += __shfl_xor(sum, 4);
        if (p == 0) invS[q] = 1.0f / sum;
        __syncthreads();

        // ---- PV MFMA: wave (wm,wn) -> queries wm*16..+15, ch wn*16..+15
        floatx4 acc = {0.f, 0.f, 0.f, 0.f};
        const ushort* arow = &Pl[(wm * 16 + col) * 168];
        const ushort* brow = &Vt[(wn * 16 + col) * 168];
#pragma unroll
        for (int s = 0; s < 5; ++s) {
            int ko = s * 32 + quad * 8;
            short8 a  = *(const short8*)(arow + ko);
            short8 bb = *(const short8*)(brow + ko);
            acc = __builtin_amdgcn_mfma_f32_16x16x32_bf16(a, bb, acc, 0, 0, 0);
        }

        // ---- epilogue: normalize + bf16 store
#pragma unroll
        for (int rg = 0; rg < 4; ++rg) {
            int qq = wm * 16 + quad * 4 + rg;
            float iv = invS[qq];
            int ii = i0 + (qq >> 3), jj = j0 + (qq & 7);
            Ab[(((b * HD_ + ii) * WD + jj)) * CD + h * HDIM + wn * 16 + col] = f2bf(acc[rg] * iv);
        }
        __syncthreads();                        // rep isolation (PV reads done)
    }
}

// ---------------- MFMA GEMM: output projection, 64x64 tiles -----------------
__global__ __launch_bounds__(256) void mfma_out64(
    const ushort* __restrict__ Ag, const ushort* __restrict__ Bt,
    const float* __restrict__ bp, float* __restrict__ out)
{
    __shared__ ushort As[64 * 64];   // 8 KB
    __shared__ ushort Bs[64 * 64];   // 8 KB
    const int t = threadIdx.x;
    const int m0 = blockIdx.y * 64, n0 = blockIdx.x * 64;
    const int lane = t & 63, w = t >> 6;
    const int lx = lane & 7, ly = lane >> 3;
    const int koff = (lx ^ ly) << 3;
    const int col = lane & 15, quad = lane >> 4;
    const int swz = (col & 7) << 4;
    const int wm = w >> 1, wn = w & 1;
    char* Ac = (char*)As;
    char* Bc = (char*)Bs;
    floatx4 acc[2][2] = {};

    for (int k0 = 0; k0 < 256; k0 += 64) {
        __syncthreads();
#pragma unroll
        for (int l = 0; l < 2; ++l) {
            int c = (w << 1) + l;
            int row = (c << 3) + ly;
            glds16(&Ag[(m0 + row) * 256 + k0 + koff], &As[c << 9]);
            glds16(&Bt[(n0 + row) * 256 + k0 + koff], &Bs[c << 9]);
        }
        __syncthreads();
#pragma unroll
        for (int kk = 0; kk < 2; ++kk) {
            const int kx = ((kk << 6) + (quad << 4)) ^ swz;
            short8 b0 = *(short8*)(Bc + ((wn << 5) + col) * 128 + kx);
            short8 b1 = *(short8*)(Bc + ((wn << 5) + 16 + col) * 128 + kx);
#pragma unroll
            for (int mt = 0; mt < 2; ++mt) {
                short8 a = *(short8*)(Ac + ((wm << 5) + (mt << 4) + col) * 128 + kx);
                acc[mt][0] = __builtin_amdgcn_mfma_f32_16x16x32_bf16(a, b0, acc[mt][0], 0, 0, 0);
                acc[mt][1] = __builtin_amdgcn_mfma_f32_16x16x32_bf16(a, b1, acc[mt][1], 0, 0, 0);
            }
        }
    }

#pragma unroll
    for (int mt = 0; mt < 2; ++mt) {
#pragma unroll
        for (int nt = 0; nt < 2; ++nt) {
            int gn = n0 + (wn << 5) + (nt << 4) + col;
            float bias = bp[gn];
#pragma unroll
            for (int rg = 0; rg < 4; ++rg) {
                int m = m0 + (wm << 5) + (mt << 4) + (quad << 2) + rg;
                out[m * 256 + gn] = acc[mt][nt][rg] + bias;
            }
        }
    }
}

extern "C" void kernel_launch(void* const* d_in, const int* in_sizes, int n_in,
                              void* d_out, int out_size, void* d_ws, size_t ws_size,
                              hipStream_t stream) {
    const float* x   = (const float*)d_in[0];
    const float* Wq  = (const float*)d_in[1];
    const float* bq  = (const float*)d_in[2];
    const float* Wk  = (const float*)d_in[3];
    const float* bk  = (const float*)d_in[4];
    const float* Wv  = (const float*)d_in[5];
    const float* bv  = (const float*)d_in[6];
    const float* rpb = (const float*)d_in[7];
    const float* Wp  = (const float*)d_in[8];
    const float* bp  = (const float*)d_in[9];
    float* out = (float*)d_out;

    // workspace layout — bf16 intermediates; ~21 MB of 256 MiB ws
    ushort* WpkT = (ushort*)d_ws;          // 81920
    ushort* WpT  = WpkT + 81920;           // 65536
    ushort* Ab   = WpT + 65536;            // 3211264
    ushort* Qb   = Ab + 3211264;           // 401408
    ushort* Kb   = Qb + BD * QK_PER_B;     // 401408
    ushort* Vb   = Kb + BD * QK_PER_B;     // 3211264
    ushort* xb   = Vb + BD * V_PER_B;      // 3211264
    float*  pb   = (float*)(xb + 3211264); // 320

    prep_all<<<(549184 + 255) / 256, 256, 0, stream>>>(
        x, Wq, Wk, Wv, bq, bk, bv, Wp, xb, WpkT, WpT, pb);

    mfma_qkv<<<dim3(5, NROWS / 128), 256, 0, stream>>>(xb, WpkT, pb, Qb, Kb, Vb);

    natten_attn4<<<dim3(7, 14, 32), 256, 0, stream>>>(Qb, Kb, Vb, rpb, Ab);

    mfma_out64<<<dim3(4, 196), 256, 0, stream>>>(Ab, WpT, bp, out);
}

// Round 9
// 113.059 us; speedup vs baseline: 1.1534x; 1.1534x over previous
//
#include <hip/hip_runtime.h>
#include <hip/hip_bf16.h>

// Problem constants (B,H,W,C) = (4,56,56,256), nh=8, K=7, lr=4, hd=32
#define BD 4
#define HD_ 56
#define WD 56
#define CD 256
#define NH 8
#define KW 7
#define LR 4
#define HDIM 32
#define MB (HD_*WD)              // 3136 rows per batch
#define NROWS (BD*MB)            // 12544 total rows
#define QK_PER_B (HD_*WD*32)     // 100352  (q/k per-batch elements)
#define V_PER_B  (HD_*WD*256)    // 802816

typedef short short8 __attribute__((ext_vector_type(8)));   // 8 bf16 (4 VGPRs)
typedef float floatx4 __attribute__((ext_vector_type(4)));  // MFMA C/D

static __device__ inline ushort f2bf(float f) {
    __hip_bfloat16 h = __float2bfloat16(f);
    return *(ushort*)&h;
}
static __device__ inline float bf2f(uint h16) {          // h16 = bf16 in low 16 bits
    union { uint u; float f; } c; c.u = h16 << 16; return c.f;
}
static __device__ inline float bf2f_hi(uint u) {         // bf16 in high 16 bits
    union { uint v; float f; } c; c.v = u & 0xffff0000u; return c.f;
}

// global -> LDS async DMA, 16B per lane. LDS dest is wave-uniform base +
// lane*16 (HW behavior); global src is per-lane.
typedef const __attribute__((address_space(1))) void* gp1_t;
typedef __attribute__((address_space(3))) void* sp3_t;
static __device__ __forceinline__ void glds16(const void* g, void* s) {
    __builtin_amdgcn_global_load_lds((gp1_t)g, (sp3_t)s, 16, 0, 0);
}

// ---------------- prep: x->bf16 + transposed bf16 weights + packed bias -----
__global__ __launch_bounds__(256) void prep_all(
    const float* __restrict__ x,
    const float* __restrict__ Wq, const float* __restrict__ Wk,
    const float* __restrict__ Wv, const float* __restrict__ bq,
    const float* __restrict__ bk, const float* __restrict__ bv,
    const float* __restrict__ Wp,
    ushort* __restrict__ xb, ushort* __restrict__ WpkT,
    ushort* __restrict__ WpT, float* __restrict__ pb)
{
    int idx = blockIdx.x * 256 + threadIdx.x;
    if (idx < 401408) {
        float4 f0 = *(const float4*)&x[idx * 8];
        float4 f1 = *(const float4*)&x[idx * 8 + 4];
        union { ushort h[8]; uint4 u; } p;
        p.h[0] = f2bf(f0.x); p.h[1] = f2bf(f0.y); p.h[2] = f2bf(f0.z); p.h[3] = f2bf(f0.w);
        p.h[4] = f2bf(f1.x); p.h[5] = f2bf(f1.y); p.h[6] = f2bf(f1.z); p.h[7] = f2bf(f1.w);
        *(uint4*)&xb[idx * 8] = p.u;
    } else if (idx < 401408 + 81920) {
        int j = idx - 401408;
        int n = j >> 8, k = j & 255;
        float v;
        if (n < 32)       v = Wq[k * 32 + n];
        else if (n < 64)  v = Wk[k * 32 + (n - 32)];
        else              v = Wv[k * 256 + (n - 64)];
        WpkT[j] = f2bf(v);
    } else if (idx < 401408 + 81920 + 65536) {
        int j = idx - (401408 + 81920);
        int n = j >> 8, k = j & 255;
        WpT[j] = f2bf(Wp[k * 256 + n]);
    } else if (idx < 401408 + 81920 + 65536 + 320) {
        int n = idx - (401408 + 81920 + 65536);
        pb[n] = (n < 32) ? bq[n] : (n < 64) ? bk[n - 32] : bv[n - 64];
    }
}

// ---------------- single-stage GEMM core: 64x64 tile, FULL K=256 in LDS -----
// A and B tiles (32 KB each) staged entirely upfront as four 64-wide K-slabs
// (each slab = the proven XOR-swizzled layout), ONE barrier, then all 32
// MFMAs. Collapses the per-block critical path from 8 barrier+vmcnt(0)
// latency episodes (4 K-steps x 2 barriers) to 1. LDS 64 KB -> 2 blocks/CU.
// Accumulation order (kb asc, kk asc) identical to the old k0-loop ->
// bit-identical results.
static __device__ __forceinline__ void gemm_stage_full(
    const ushort* __restrict__ Ag, const ushort* __restrict__ Bg,
    ushort (*As)[64 * 64], ushort (*Bs)[64 * 64],
    int m0, int n0, int t)
{
    const int lane = t & 63, w = t >> 6;
    const int lx = lane & 7, ly = lane >> 3;
    const int koff = (lx ^ ly) << 3;
#pragma unroll
    for (int kb = 0; kb < 4; ++kb) {
#pragma unroll
        for (int l = 0; l < 2; ++l) {
            int c = (w << 1) + l;
            int row = (c << 3) + ly;
            glds16(&Ag[(m0 + row) * 256 + (kb << 6) + koff], &As[kb][c << 9]);
            glds16(&Bg[(n0 + row) * 256 + (kb << 6) + koff], &Bs[kb][c << 9]);
        }
    }
}

static __device__ __forceinline__ void gemm_compute_full(
    ushort (*As)[64 * 64], ushort (*Bs)[64 * 64], int t, floatx4 (&acc)[2][2])
{
    const int lane = t & 63, w = t >> 6;
    const int col = lane & 15, quad = lane >> 4;
    const int swz = (col & 7) << 4;
    const int wm = w >> 1, wn = w & 1;
#pragma unroll
    for (int kb = 0; kb < 4; ++kb) {
        char* Ac = (char*)As[kb];
        char* Bc = (char*)Bs[kb];
#pragma unroll
        for (int kk = 0; kk < 2; ++kk) {
            const int kx = ((kk << 6) + (quad << 4)) ^ swz;
            short8 b0 = *(short8*)(Bc + ((wn << 5) + col) * 128 + kx);
            short8 b1 = *(short8*)(Bc + ((wn << 5) + 16 + col) * 128 + kx);
#pragma unroll
            for (int mt = 0; mt < 2; ++mt) {
                short8 a = *(short8*)(Ac + ((wm << 5) + (mt << 4) + col) * 128 + kx);
                acc[mt][0] = __builtin_amdgcn_mfma_f32_16x16x32_bf16(a, b0, acc[mt][0], 0, 0, 0);
                acc[mt][1] = __builtin_amdgcn_mfma_f32_16x16x32_bf16(a, b1, acc[mt][1], 0, 0, 0);
            }
        }
    }
}

// ---------------- MFMA GEMM: QKV projection, single-stage 64x64 -------------
// grid (5, 196): n0=0 block covers Q(0..31)+K(32..63); n0>=64 -> V.
__global__ __launch_bounds__(256) void mfma_qkv64(
    const ushort* __restrict__ xb, const ushort* __restrict__ Bt,
    const float* __restrict__ pb, ushort* __restrict__ Qb,
    ushort* __restrict__ Kb, ushort* __restrict__ Vb)
{
    __shared__ ushort As[4][64 * 64];   // 32 KB
    __shared__ ushort Bs[4][64 * 64];   // 32 KB
    const int t = threadIdx.x;
    const int m0 = blockIdx.y * 64, n0 = blockIdx.x * 64;

    gemm_stage_full(xb, Bt, As, Bs, m0, n0, t);
    __syncthreads();

    floatx4 acc[2][2] = {};
    gemm_compute_full(As, Bs, t, acc);

    const int lane = t & 63, w = t >> 6;
    const int col = lane & 15, quad = lane >> 4;
    const int wm = w >> 1, wn = w & 1;
#pragma unroll
    for (int mt = 0; mt < 2; ++mt) {
#pragma unroll
        for (int nt = 0; nt < 2; ++nt) {
            int gn = n0 + (wn << 5) + (nt << 4) + col;
            float bias = pb[gn];
#pragma unroll
            for (int rg = 0; rg < 4; ++rg) {
                int m = m0 + (wm << 5) + (mt << 4) + (quad << 2) + rg;
                ushort h = f2bf(acc[mt][nt][rg] + bias);
                if (gn < 32)        Qb[m * 32 + gn] = h;
                else if (gn < 64)   Kb[m * 32 + (gn - 32)] = h;
                else                Vb[m * 256 + (gn - 64)] = h;
            }
        }
    }
}

// ---------------- MFMA GEMM: output projection, single-stage 64x64 ----------
__global__ __launch_bounds__(256) void mfma_outF(
    const ushort* __restrict__ Ag, const ushort* __restrict__ Bt,
    const float* __restrict__ bp, float* __restrict__ out)
{
    __shared__ ushort As[4][64 * 64];   // 32 KB
    __shared__ ushort Bs[4][64 * 64];   // 32 KB
    const int t = threadIdx.x;
    const int m0 = blockIdx.y * 64, n0 = blockIdx.x * 64;

    gemm_stage_full(Ag, Bt, As, Bs, m0, n0, t);
    __syncthreads();

    floatx4 acc[2][2] = {};
    gemm_compute_full(As, Bs, t, acc);

    const int lane = t & 63, w = t >> 6;
    const int col = lane & 15, quad = lane >> 4;
    const int wm = w >> 1, wn = w & 1;
#pragma unroll
    for (int mt = 0; mt < 2; ++mt) {
#pragma unroll
        for (int nt = 0; nt < 2; ++nt) {
            int gn = n0 + (wn << 5) + (nt << 4) + col;
            float bias = bp[gn];
#pragma unroll
            for (int rg = 0; rg < 4; ++rg) {
                int m = m0 + (wm << 5) + (mt << 4) + (quad << 2) + rg;
                out[m * 256 + gn] = acc[mt][nt][rg] + bias;
            }
        }
    }
}

// ---------------- NATTEN attention v4 (1 rep, proven; ~9 us measured R8) ----
__global__ __launch_bounds__(256) void natten_attn4(
    const ushort* __restrict__ Qb, const ushort* __restrict__ Kb,
    const ushort* __restrict__ Vb, const float* __restrict__ rpb,
    ushort* __restrict__ Ab)
{
    __shared__ __align__(16) ushort Pl[32 * 168];   // 10752 B  P[q][key]
    __shared__ __align__(16) ushort Vt[32 * 168];   // 10752 B  V^T[ch][key]
    __shared__ float4 Ksf[140];                     // 2240 B
    __shared__ float  Rs[169];                      // 676 B
    __shared__ float  invS[32];                     // 128 B

    const int tj = blockIdx.x, ti = blockIdx.y;
    const int h = blockIdx.z & 7, b = blockIdx.z >> 3;
    const int t = threadIdx.x;
    const int i0 = ti * 4, j0 = tj * 8;
    const int rs = min(max(i0 - 3, 0), HD_ - 10);
    const int cs = min(max(j0 - 3, 0), WD - 14);

    const ushort* kb = Kb + (size_t)b * QK_PER_B + h * (HD_ * WD * LR);
    const ushort* vb = Vb + (size_t)b * V_PER_B + h * (HD_ * WD * HDIM);

#pragma unroll
    for (int it = 0; it < 3; ++it) {
        int idx = t + (it << 8);
        if (idx < 672) {
            *(uint4*)&Pl[idx << 3] = make_uint4(0, 0, 0, 0);
            *(uint4*)&Vt[idx << 3] = make_uint4(0, 0, 0, 0);
        }
    }
    __syncthreads();

    if (t < 140) {
        int r = t / 14, c = t % 14;
        uint2 kr = *(const uint2*)&kb[(rs + r) * (WD * LR) + (cs + c) * LR];
        Ksf[t] = make_float4(bf2f(kr.x & 0xffff), bf2f_hi(kr.x),
                             bf2f(kr.y & 0xffff), bf2f_hi(kr.y));
    }
    if (t < 169) Rs[t] = rpb[h * 169 + t];
#pragma unroll
    for (int it = 0; it < 3; ++it) {
        int idx = t + (it << 8);
        if (idx < 560) {
            int oct = idx / 140, pos = idx % 140;
            int r = pos / 14, c = pos % 14;
            union { uint4 u; ushort hh[8]; } vv;
            vv.u = *(const uint4*)&vb[(rs + r) * (WD * HDIM) + (cs + c) * HDIM + oct * 8];
            ushort* cp = &Vt[(oct * 8) * 168 + pos];
#pragma unroll
            for (int e = 0; e < 8; ++e) cp[e * 168] = vv.hh[e];
        }
    }

    const int q  = t >> 3, p = t & 7;
    const int qi = q >> 3, qj = q & 7;
    const int i = i0 + qi, j = j0 + qj;
    uint2 qr2 = *(const uint2*)&Qb[(size_t)b * QK_PER_B + h * (HD_ * WD * LR) + i * (WD * LR) + j * LR];
    __syncthreads();

    const int sh = min(max(i - 3, 0), HD_ - KW);
    const int sw = min(max(j - 3, 0), WD - KW);
    const int oh = sh - rs, ow = sw - cs;
    const int rb0 = (sh - i + 6) * 13 + (sw - j + 6);
    const float scale = 0.17677669529663687f;
    float qx = bf2f(qr2.x & 0xffff) * scale, qy = bf2f_hi(qr2.x) * scale;
    float qz = bf2f(qr2.y & 0xffff) * scale, qw = bf2f_hi(qr2.y) * scale;

    float sum = 0.f;
    if (p < 7) {
        int kpos  = (oh + p) * 14 + ow;
        int rbase = rb0 + p * 13;
        ushort* prow = &Pl[q * 168 + kpos];
#pragma unroll
        for (int kw = 0; kw < 7; ++kw) {
            float4 kf = Ksf[kpos + kw];
            float d = Rs[rbase + kw];
            d = fmaf(qx, kf.x, d);
            d = fmaf(qy, kf.y, d);
            d = fmaf(qz, kf.z, d);
            d = fmaf(qw, kf.w, d);
            float e = __expf(d);
            sum += e;
            prow[kw] = f2bf(e);
        }
    }
    sum += __shfl_xor(sum, 1);
    sum += __shfl_xor(sum, 2);
    sum += __shfl_xor(sum, 4);
    if (p == 0) invS[q] = 1.0f / sum;
    __syncthreads();

    const int lane = t & 63, w = t >> 6;
    const int col = lane & 15, quad = lane >> 4;
    const int wm = w & 1, wn = w >> 1;
    floatx4 acc = {0.f, 0.f, 0.f, 0.f};
    const ushort* arow = &Pl[(wm * 16 + col) * 168];
    const ushort* brow = &Vt[(wn * 16 + col) * 168];
#pragma unroll
    for (int s = 0; s < 5; ++s) {
        int ko = s * 32 + quad * 8;
        short8 a  = *(const short8*)(arow + ko);
        short8 bb = *(const short8*)(brow + ko);
        acc = __builtin_amdgcn_mfma_f32_16x16x32_bf16(a, bb, acc, 0, 0, 0);
    }

#pragma unroll
    for (int rg = 0; rg < 4; ++rg) {
        int qq = wm * 16 + quad * 4 + rg;
        float iv = invS[qq];
        int ii = i0 + (qq >> 3), jj = j0 + (qq & 7);
        Ab[(((b * HD_ + ii) * WD + jj)) * CD + h * HDIM + wn * 16 + col] = f2bf(acc[rg] * iv);
    }
}

extern "C" void kernel_launch(void* const* d_in, const int* in_sizes, int n_in,
                              void* d_out, int out_size, void* d_ws, size_t ws_size,
                              hipStream_t stream) {
    const float* x   = (const float*)d_in[0];
    const float* Wq  = (const float*)d_in[1];
    const float* bq  = (const float*)d_in[2];
    const float* Wk  = (const float*)d_in[3];
    const float* bk  = (const float*)d_in[4];
    const float* Wv  = (const float*)d_in[5];
    const float* bv  = (const float*)d_in[6];
    const float* rpb = (const float*)d_in[7];
    const float* Wp  = (const float*)d_in[8];
    const float* bp  = (const float*)d_in[9];
    float* out = (float*)d_out;

    // workspace layout — bf16 intermediates; ~21 MB of 256 MiB ws
    ushort* WpkT = (ushort*)d_ws;          // 81920
    ushort* WpT  = WpkT + 81920;           // 65536
    ushort* Ab   = WpT + 65536;            // 3211264
    ushort* Qb   = Ab + 3211264;           // 401408
    ushort* Kb   = Qb + BD * QK_PER_B;     // 401408
    ushort* Vb   = Kb + BD * QK_PER_B;     // 3211264
    ushort* xb   = Vb + BD * V_PER_B;      // 3211264
    float*  pb   = (float*)(xb + 3211264); // 320

    prep_all<<<(549184 + 255) / 256, 256, 0, stream>>>(
        x, Wq, Wk, Wv, bq, bk, bv, Wp, xb, WpkT, WpT, pb);

    mfma_qkv64<<<dim3(5, 196), 256, 0, stream>>>(xb, WpkT, pb, Qb, Kb, Vb);

    natten_attn4<<<dim3(7, 14, 32), 256, 0, stream>>>(Qb, Kb, Vb, rpb, Ab);

    mfma_outF<<<dim3(4, 196), 256, 0, stream>>>(Ab, WpT, bp, out);
}